// Round 5
// baseline (193.927 us; speedup 1.0000x reference)
//
#include <hip/hip_runtime.h>
#include <hip/hip_bf16.h>
#include <stdint.h>

typedef __bf16 bf16_t;
typedef __bf16 bf16x8 __attribute__((ext_vector_type(8)));
typedef __bf16 bf16x4 __attribute__((ext_vector_type(4)));
typedef float  f32x4  __attribute__((ext_vector_type(4)));

#define AS_GLOBAL __attribute__((address_space(1)))
#define AS_LDS    __attribute__((address_space(3)))
#define VMW(N) asm volatile("s_waitcnt vmcnt(" #N ")" ::: "memory")

static constexpr int CCH   = 256;
static constexpr int HP    = 34;
static constexpr int PLANE = HP * HP;   // 1156 padded pixels per image

// ---------------- BN parameter folding ----------------
__global__ void prep_params_k(const float* g1, const float* b1, const float* m1, const float* v1,
                              const float* g2, const float* b2, const float* m2, const float* v2,
                              float* prm) {
  int i = threadIdx.x;
  float i1 = g1[i] * rsqrtf(v1[i] + 1e-5f);
  prm[i]       = i1;
  prm[256 + i] = b1[i] - m1[i] * i1;
  float i2 = g2[i] * rsqrtf(v2[i] + 1e-5f);
  prm[512 + i] = i2;
  prm[768 + i] = b2[i] - m2[i] * i2;
}

// ---------------- masked weights -> bf16, [khw][co][ci] ----------------
__global__ __launch_bounds__(256) void prep_weights_k(const float* __restrict__ w,
                                                      const float* __restrict__ msk,
                                                      bf16_t* __restrict__ out) {
  int idx = blockIdx.x * 256 + threadIdx.x;
  const float* wp = w + (long)idx * 9;
  const float* mp = msk + (long)idx * 9;
#pragma unroll
  for (int khw = 0; khw < 9; ++khw)
    out[khw * 65536 + idx] = (bf16_t)(wp[khw] * mp[khw]);
}

// ---------------- zero only the pad borders of both intermediates ----------------
__global__ __launch_bounds__(256) void zero_borders_k(bf16_t* __restrict__ t0p,
                                                      bf16_t* __restrict__ t1p) {
  const int bid = blockIdx.x;               // 128: image n = bid>>1, buffer = bid&1
  bf16_t* base = ((bid & 1) ? t1p : t0p) + (long)(bid >> 1) * PLANE * CCH;
  for (int i = threadIdx.x; i < 132 * 32; i += 256) {
    int pix = i >> 5, c16 = i & 31;
    int r, col;
    if (pix < 34)       { r = 0;           col = pix; }
    else if (pix < 68)  { r = 33;          col = pix - 34; }
    else if (pix < 100) { r = pix - 68 + 1; col = 0; }
    else                { r = pix - 100 + 1; col = 33; }
    *(f32x4*)&base[(r * HP + col) * CCH + c16 * 8] = f32x4{0.f, 0.f, 0.f, 0.f};
  }
}

// ------- relu(bn1(x)) -> bf16, NCHW -> channels-last padded [n][34*34][256] -------
__global__ __launch_bounds__(256) void prep_input_k(const float* __restrict__ x,
                                                    const float* __restrict__ prm,
                                                    bf16_t* __restrict__ t0p) {
  __shared__ __align__(16) bf16_t tile[64 * 256];
  const int tid = threadIdx.x;
  const int bid = blockIdx.x;
  const int n   = bid >> 4;
  const int p0  = (bid & 15) << 6;
  const int px    = tid & 63;
  const int cbase = tid >> 6;
  for (int r = 0; r < 64; ++r) {
    int ci = r * 4 + cbase;
    float v = x[((n * 256 + ci) << 10) + p0 + px];
    float y = fmaxf(v * prm[ci] + prm[256 + ci], 0.f);
    int byte = px * 512 + ((ci * 2) ^ ((px & 7) << 4));
    *(bf16_t*)((char*)tile + byte) = (bf16_t)y;
  }
  __syncthreads();
  for (int j = 0; j < 8; ++j) {
    int off  = j * 256 + tid;
    int pix  = off >> 5;
    int c16  = off & 31;
    int byte = pix * 512 + ((c16 * 16) ^ ((pix & 7) << 4));
    bf16x8 v = *(const bf16x8*)((char*)tile + byte);
    int p = p0 + pix;
    long gp = ((long)n * PLANE + ((p >> 5) + 1) * HP + (p & 31) + 1) * CCH + c16 * 8;
    *(bf16x8*)(t0p + gp) = v;
  }
}

// ------------ implicit-GEMM 3x3 conv: 256co x 256px block, 8-phase template ------
// 8 waves (2M x 4N), wave tile 128co x 64px. 72 K-tiles (8 ci-chunks x 9 taps,
// K=32), 2 phases each (16 MFMA/wave). A [256co][32ci] triple-buffered, staged 2
// tiles ahead (1 half-tile per phase). B patch [10r][34c][32ci] double-buffered
// per ci-chunk (3 loads at taps 1/3/5). Template phase op order per m201; counted
// vmcnt between P1 MFMA and barrier: A(k+1) has {2 A-halves + optional B} younger.
template <int EPI>
__global__ __launch_bounds__(512, 2) void conv3x3_k(const bf16_t* __restrict__ inp,
                                                    const bf16_t* __restrict__ wts,
                                                    const float* __restrict__ prm,
                                                    const float* __restrict__ resid,
                                                    bf16_t* __restrict__ out_cl,
                                                    float* __restrict__ out_f) {
  __shared__ __align__(128) bf16_t As[3][8192];    // 3 x 16 KB  [256co][32ci]
  __shared__ __align__(128) bf16_t Bs[2][12288];   // 2 x 24 KB  (1360 granules + slack)

  const int tid  = threadIdx.x;
  const int lane = tid & 63;
  const int wid  = tid >> 6;     // 0..7
  const int wm   = wid >> 2;     // co half (128)
  const int wn   = wid & 3;      // px quarter (64)

  const int bid = blockIdx.x;    // 256 = 64 n * 4 row-groups  (1 block/CU)
  const int n   = bid >> 2;
  const int hb  = (bid & 3) << 3;  // padded top row of this block's 10-row patch

  const int swz8 = (((lane & 3) ^ ((lane >> 2) & 3) ^ (lane >> 4)) << 3);
  const int l15  = lane & 15;
  const int k4   = lane >> 4;

  f32x4 acc[8][4];
#pragma unroll
  for (int i = 0; i < 8; ++i)
#pragma unroll
    for (int j = 0; j < 4; ++j) acc[i][j] = f32x4{0.f, 0.f, 0.f, 0.f};

  bf16x8 av[8], bv[4];

  auto stageA_half = [&](int abuf, int c, int t, int half) {  // 1 load/thread
    const int ch  = wid * 2 + half;          // 0..15, 16 rows each
    const int row = ch * 16 + (lane >> 2);
    const bf16_t* ga = wts + ((t * CCH + row) * CCH + (c << 5) + swz8);
    __builtin_amdgcn_global_load_lds((const AS_GLOBAL void*)ga,
                                     (AS_LDS void*)(&As[abuf][ch * 512]), 16, 0, 0);
  };

  auto stageB = [&](int bbuf, int c, int j) {  // 1 load/thread
    const int ibase = wid * 3 + j;             // 0..23
    int s = (ibase << 6) + lane;
    if (s > 1359) s = 1359;                    // tail slack, never read
    const int r   = s / 136;
    const int rem = s - r * 136;
    const int cc  = rem >> 2;
    const int ks  = ((rem & 3) - (cc >> 1)) & 3;   // inverse of read swizzle
    const bf16_t* gb = inp + ((n * PLANE + (hb + r) * HP + cc) * CCH + (c << 5) + (ks << 3));
    __builtin_amdgcn_global_load_lds((const AS_GLOBAL void*)gb,
                                     (AS_LDS void*)(&Bs[bbuf][ibase * 512]), 16, 0, 0);
  };

#define LDA(AB) do {                                                                \
    _Pragma("unroll") for (int mi = 0; mi < 8; ++mi)                                \
      av[mi] = *(const bf16x8*)&As[AB][((wm * 128 + mi * 16 + l15) << 5) + swz8];   \
  } while (0)

#define LDB(T, BB) do {                                                             \
    constexpr int KH = (T) / 3, KW = (T) % 3;                                       \
    _Pragma("unroll") for (int ni = 0; ni < 4; ++ni) {                              \
      const int p_    = (wn << 6) + (ni << 4) + l15;                                \
      const int cc_   = (p_ & 31) + KW;                                             \
      const int slot_ = ((p_ >> 5) + KH) * 136 + (cc_ << 2) + ((k4 + (cc_ >> 1)) & 3); \
      bv[ni] = *(const bf16x8*)&Bs[BB][slot_ << 3];                                 \
    }                                                                               \
  } while (0)

#define MFMA8(NJ) do {                                                              \
    _Pragma("unroll") for (int mi = 0; mi < 8; ++mi)                                \
      acc[mi][NJ] = __builtin_amdgcn_mfma_f32_16x16x32_bf16(av[mi], bv[NJ], acc[mi][NJ], 0, 0, 0); \
  } while (0)

  // one K-tile = 2 phases. t literal, c runtime, CL7 literal (c<7?)
#define TILE(t, CL7) do {                                                           \
    constexpr int AB  = (t) % 3;                                                    \
    constexpr int AB2 = ((t) + 2) % 3;                                              \
    const int bb = c & 1;                                                           \
    /* ---- P0: frag reads + stage issues ---- */                                   \
    LDA(AB); LDB(t, bb);                                                            \
    if ((CL7) && ((t) == 1 || (t) == 3 || (t) == 5)) stageB(bb ^ 1, c + 1, ((t) - 1) / 2); \
    if ((CL7) || (t) <= 6) {                                                        \
      if ((t) <= 6) stageA_half(AB2, c, (t) + 2, 0);                                \
      else          stageA_half(AB2, c + 1, (t) - 7, 0);                            \
    }                                                                               \
    __builtin_amdgcn_s_barrier();                                                   \
    asm volatile("s_waitcnt lgkmcnt(0)" ::: "memory");                              \
    __builtin_amdgcn_sched_barrier(0);                                              \
    __builtin_amdgcn_s_setprio(1); MFMA8(0); MFMA8(1); __builtin_amdgcn_s_setprio(0); \
    __builtin_amdgcn_s_barrier();                                                   \
    /* ---- P1: second half-tile stage + MFMA ---- */                               \
    if ((CL7) || (t) <= 6) {                                                        \
      if ((t) <= 6) stageA_half(AB2, c, (t) + 2, 1);                                \
      else          stageA_half(AB2, c + 1, (t) - 7, 1);                            \
    }                                                                               \
    __builtin_amdgcn_s_setprio(1); MFMA8(2); MFMA8(3); __builtin_amdgcn_s_setprio(0); \
    if ((CL7) || (t) <= 6) {                                                        \
      if ((CL7) && ((t) == 1 || (t) == 3 || (t) == 5)) { VMW(3); } else { VMW(2); } \
    } else if ((t) == 7) { VMW(0); }                                                \
    __builtin_amdgcn_s_barrier();                                                   \
  } while (0)

  // prologue: B(chunk0) + A(tile0) + A(tile1); A(1) left in flight
  stageB(0, 0, 0); stageB(0, 0, 1); stageB(0, 0, 2);
  stageA_half(0, 0, 0, 0); stageA_half(0, 0, 0, 1);
  stageA_half(1, 0, 1, 0); stageA_half(1, 0, 1, 1);
  VMW(2);
  __builtin_amdgcn_s_barrier();

  for (int c = 0; c < 7; ++c) {
    TILE(0, 1); TILE(1, 1); TILE(2, 1); TILE(3, 1); TILE(4, 1);
    TILE(5, 1); TILE(6, 1); TILE(7, 1); TILE(8, 1);
  }
  {
    const int c = 7;
    TILE(0, 0); TILE(1, 0); TILE(2, 0); TILE(3, 0); TILE(4, 0);
    TILE(5, 0); TILE(6, 0); TILE(7, 0); TILE(8, 0);
  }

#undef TILE
#undef LDA
#undef LDB
#undef MFMA8

  // C/D layout: col(pixel) = lane&15, row(co) = (lane>>4)*4 + reg
  if (EPI == 0) {
#pragma unroll
    for (int mi = 0; mi < 8; ++mi) {
      const int co_b = wm * 128 + mi * 16 + ((lane >> 4) << 2);
      const float s0 = prm[co_b], s1 = prm[co_b + 1], s2 = prm[co_b + 2], s3 = prm[co_b + 3];
      const float t0 = prm[256 + co_b], t1 = prm[256 + co_b + 1],
                  t2 = prm[256 + co_b + 2], t3 = prm[256 + co_b + 3];
#pragma unroll
      for (int ni = 0; ni < 4; ++ni) {
        f32x4 v = acc[mi][ni];
        const int p  = (wn << 6) + (ni << 4) + l15;
        const int pr = p >> 5, pc = p & 31;
        bf16x4 pk;
        pk[0] = (bf16_t)fmaxf(v[0] * s0 + t0, 0.f);
        pk[1] = (bf16_t)fmaxf(v[1] * s1 + t1, 0.f);
        pk[2] = (bf16_t)fmaxf(v[2] * s2 + t2, 0.f);
        pk[3] = (bf16_t)fmaxf(v[3] * s3 + t3, 0.f);
        *(bf16x4*)&out_cl[(n * PLANE + (hb + pr + 1) * HP + pc + 1) * CCH + co_b] = pk;
      }
    }
  } else {
#pragma unroll
    for (int mi = 0; mi < 8; ++mi) {
      const int co_b = wm * 128 + mi * 16 + ((lane >> 4) << 2);
#pragma unroll
      for (int ni = 0; ni < 4; ++ni) {
        f32x4 v = acc[mi][ni];
        const int p  = (wn << 6) + (ni << 4) + l15;
        const int gp = ((n * CCH + co_b) << 10) + (hb << 5) + p;
        out_f[gp]        = v[0] + resid[gp];
        out_f[gp + 1024] = v[1] + resid[gp + 1024];
        out_f[gp + 2048] = v[2] + resid[gp + 2048];
        out_f[gp + 3072] = v[3] + resid[gp + 3072];
      }
    }
  }
}

extern "C" void kernel_launch(void* const* d_in, const int* in_sizes, int n_in,
                              void* d_out, int out_size, void* d_ws, size_t ws_size,
                              hipStream_t stream) {
  const float* x  = (const float*)d_in[0];
  const float* g1 = (const float*)d_in[1];
  const float* b1 = (const float*)d_in[2];
  const float* m1 = (const float*)d_in[3];
  const float* v1 = (const float*)d_in[4];
  const float* w1 = (const float*)d_in[5];
  const float* k1 = (const float*)d_in[6];
  const float* g2 = (const float*)d_in[7];
  const float* b2 = (const float*)d_in[8];
  const float* m2 = (const float*)d_in[9];
  const float* v2 = (const float*)d_in[10];
  const float* w2 = (const float*)d_in[11];
  const float* k2 = (const float*)d_in[12];

  char* ws = (char*)d_ws;
  const size_t T0P_B = (size_t)64 * PLANE * CCH * 2;
  bf16_t* t0p = (bf16_t*)ws;
  bf16_t* t1p = (bf16_t*)(ws + T0P_B);
  bf16_t* mw1 = (bf16_t*)(ws + 2 * T0P_B);
  bf16_t* mw2 = (bf16_t*)(ws + 2 * T0P_B + 1179648);
  float*  prm = (float*)(ws + 2 * T0P_B + 2 * 1179648);

  prep_params_k<<<1, 256, 0, stream>>>(g1, b1, m1, v1, g2, b2, m2, v2, prm);
  zero_borders_k<<<128, 256, 0, stream>>>(t0p, t1p);
  prep_weights_k<<<256, 256, 0, stream>>>(w1, k1, mw1);
  prep_weights_k<<<256, 256, 0, stream>>>(w2, k2, mw2);
  prep_input_k<<<1024, 256, 0, stream>>>(x, prm, t0p);

  conv3x3_k<0><<<256, 512, 0, stream>>>(t0p, mw1, prm + 512, nullptr, t1p, nullptr);
  conv3x3_k<1><<<256, 512, 0, stream>>>(t1p, mw2, nullptr, x, nullptr, (float*)d_out);
}